// Round 17
// baseline (335.749 us; speedup 1.0000x reference)
//
#include <hip/hip_runtime.h>

#define TT 2048
#define DM 1024
#define HPAD 2816
#define HID 2730
#define SM_C 0.18033688f   // 0.125 * log2(e)

typedef __attribute__((ext_vector_type(4))) float f32x4;
typedef __attribute__((ext_vector_type(8))) short bf16x8;

static __device__ __forceinline__ float bf2f(short u) {
    union { float f; unsigned int i; } c; c.i = ((unsigned int)(unsigned short)u) << 16; return c.f;
}
static __device__ __forceinline__ short f2bf(float f) {
    union { float f; unsigned int i; } c; c.f = f;
    unsigned int i = c.i;
    unsigned int r = (i + 0x7fffu + ((i >> 16) & 1u)) >> 16;
    return (short)r;
}
static __device__ __forceinline__ unsigned int fbits(float f) {
    union { float f; unsigned int i; } c; c.f = f;
    return c.i;
}

static __device__ __forceinline__ void gload_lds16(const void* g, void* l) {
    __builtin_amdgcn_global_load_lds(
        (const __attribute__((address_space(1))) unsigned int*)g,
        (__attribute__((address_space(3))) unsigned int*)l, 16, 0, 0);
}

// ---------------- merged weight transpose + cast (+pad), all 5 weights in one launch.
__global__ __launch_bounds__(256) void wprep_all(
    const float* __restrict__ w_attn, const float* __restrict__ w_proj,
    const float* __restrict__ w1, const float* __restrict__ w2, const float* __restrict__ w3,
    short* __restrict__ wattn_t, short* __restrict__ wproj_t,
    short* __restrict__ w1t, short* __restrict__ w2t, short* __restrict__ w3t)
{
    __shared__ float tile[32][33];
    int id = blockIdx.x;
    const float* in; short* out; int K, N, Kpad, Npad, nbx;
    if (id < 3072)      {            in = w_attn; out = wattn_t; K = 1024; N = 3072; Kpad = 1024; Npad = 3072; nbx = 32; }
    else if (id < 4096) { id -= 3072; in = w_proj; out = wproj_t; K = 1024; N = 1024; Kpad = 1024; Npad = 1024; nbx = 32; }
    else if (id < 6912) { id -= 4096; in = w1;     out = w1t;     K = 1024; N = HID;  Kpad = 1024; Npad = HPAD; nbx = 32; }
    else if (id < 9728) { id -= 6912; in = w2;     out = w2t;     K = 1024; N = HID;  Kpad = 1024; Npad = HPAD; nbx = 32; }
    else                { id -= 9728; in = w3;     out = w3t;     K = HID;  N = 1024; Kpad = HPAD; Npad = 1024; nbx = 88; }
    int kb = (id % nbx) * 32, nb = (id / nbx) * 32;
    int tx = threadIdx.x, ty = threadIdx.y; // 32 x 8
    #pragma unroll
    for (int i = 0; i < 32; i += 8) {
        int k = kb + ty + i, n = nb + tx;
        float v = (k < K && n < N) ? in[(size_t)k * N + n] : 0.f;
        tile[tx][ty + i] = v;
    }
    __syncthreads();
    #pragma unroll
    for (int i = 0; i < 32; i += 8) {
        int n = nb + ty + i, k = kb + tx;
        if (n < Npad && k < Kpad) out[(size_t)n * Kpad + k] = f2bf(tile[ty + i][tx]);
    }
}

// ---------------- fused double RMSNorm: x f32 [8192,1024] -> xn1, xn2 bf16
__global__ __launch_bounds__(256) void rmsnorm2(const float* __restrict__ x,
    const float* __restrict__ g1, const float* __restrict__ g2,
    short* __restrict__ xn1, short* __restrict__ xn2) {
    int row = blockIdx.x;
    const float* xr = x + (size_t)row * DM;
    int t = threadIdx.x;
    float4 v = ((const float4*)xr)[t];
    float ss = v.x*v.x + v.y*v.y + v.z*v.z + v.w*v.w;
    #pragma unroll
    for (int off = 1; off < 64; off <<= 1) ss += __shfl_xor(ss, off);
    __shared__ float red[4];
    if ((t & 63) == 0) red[t >> 6] = ss;
    __syncthreads();
    float tot = red[0] + red[1] + red[2] + red[3];
    float rs = rsqrtf(tot * (1.0f / DM) + 1e-6f);
    float4 G1 = ((const float4*)g1)[t];
    float4 G2 = ((const float4*)g2)[t];
    union { short s[4]; int2 v; } o1, o2;
    o1.s[0] = f2bf(v.x * rs * G1.x); o1.s[1] = f2bf(v.y * rs * G1.y);
    o1.s[2] = f2bf(v.z * rs * G1.z); o1.s[3] = f2bf(v.w * rs * G1.w);
    o2.s[0] = f2bf(v.x * rs * G2.x); o2.s[1] = f2bf(v.y * rs * G2.y);
    o2.s[2] = f2bf(v.z * rs * G2.z); o2.s[3] = f2bf(v.w * rs * G2.w);
    *(int2*)(xn1 + (size_t)row * DM + t * 4) = o1.v;
    *(int2*)(xn2 + (size_t)row * DM + t * 4) = o2.v;
}

// ---------------- bf16 GEMM, BM=256 x BN=128, BK=64, 512 thr / 8 waves (4m x 2n).
// EPI 5: Cb = acc bf16, cols < 1024 pre-scaled by SM_C (qkv: Q prescale)
template<int EPI>
__global__ __launch_bounds__(512, 4) void gemm256(
    const short* __restrict__ A, const short* __restrict__ Bt,
    short* __restrict__ Cb, int N, int K)
{
    __shared__ short As[256 * 64];   // 32KB
    __shared__ short Bs[128 * 64];   // 16KB
    int t = threadIdx.x;
    int wid = t >> 6, l = t & 63;
    int wm = wid >> 1, wn = wid & 1;

    int nwg = gridDim.x, bid = blockIdx.x;
    int wg = (bid & 7) * (nwg >> 3) + (bid >> 3);   // XCD swizzle (grids %8==0)
    int tiles_n = N >> 7;
    int tm = wg / tiles_n, tn = wg % tiles_n;

    f32x4 acc[4][4];
    #pragma unroll
    for (int m = 0; m < 4; m++)
        #pragma unroll
        for (int n = 0; n < 4; n++) acc[m][n] = (f32x4){0.f, 0.f, 0.f, 0.f};

    const short* Apan = A + (size_t)(tm * 256) * K;
    const short* Bpan = Bt + (size_t)(tn * 128) * K;

    for (int kt = 0; kt < K; kt += 64) {
        __syncthreads();
        #pragma unroll
        for (int i = 0; i < 4; i++) {
            int lin = i * 512 + t;            // 0..2047 -> A rows 0..255
            int row = lin >> 3;
            int slot = lin & 7;
            int src = slot ^ (row & 7);       // pre-swizzled source, linear LDS dest
            gload_lds16(Apan + (size_t)row * K + kt + src * 8, (char*)As + lin * 16);
        }
        #pragma unroll
        for (int i = 0; i < 2; i++) {
            int lin = i * 512 + t;            // 0..1023 -> B rows 0..127
            int row = lin >> 3;
            int slot = lin & 7;
            int src = slot ^ (row & 7);
            gload_lds16(Bpan + (size_t)row * K + kt + src * 8, (char*)Bs + lin * 16);
        }
        __syncthreads();
        #pragma unroll
        for (int ks = 0; ks < 2; ks++) {
            bf16x8 af[4], bfr[4];
            #pragma unroll
            for (int m = 0; m < 4; m++) {
                int row = wm * 64 + m * 16 + (l & 15);
                af[m] = *(const bf16x8*)((char*)As + row * 128 + ((ks * 64 + (l >> 4) * 16) ^ ((row & 7) << 4)));
            }
            #pragma unroll
            for (int n = 0; n < 4; n++) {
                int row = wn * 64 + n * 16 + (l & 15);
                bfr[n] = *(const bf16x8*)((char*)Bs + row * 128 + ((ks * 64 + (l >> 4) * 16) ^ ((row & 7) << 4)));
            }
            __builtin_amdgcn_s_setprio(1);
            #pragma unroll
            for (int m = 0; m < 4; m++)
                #pragma unroll
                for (int n = 0; n < 4; n++)
                    acc[m][n] = __builtin_amdgcn_mfma_f32_16x16x32_bf16(af[m], bfr[n], acc[m][n], 0, 0, 0);
            __builtin_amdgcn_s_setprio(0);
        }
    }

    bool qcols = (EPI == 5) && (tn < 8);   // block-uniform: qkv cols < 1024
    #pragma unroll
    for (int m = 0; m < 4; m++)
        #pragma unroll
        for (int n = 0; n < 4; n++)
            #pragma unroll
            for (int r = 0; r < 4; r++) {
                int row = tm * 256 + wm * 64 + m * 16 + (l >> 4) * 4 + r;
                int col = tn * 128 + wn * 64 + n * 16 + (l & 15);
                size_t idx = (size_t)row * N + col;
                float v = acc[m][n][r];
                if constexpr (EPI == 5) Cb[idx] = f2bf(qcols ? v * SM_C : v);
                else Cb[idx] = f2bf(v);
            }
}

// ---------------- fused attn-proj + MLP-down + residual (128x128, 256 thr, grid 512):
// out = x + yb@wprojT + hb@w3T
__global__ __launch_bounds__(256) void gemm_fuse(
    const short* __restrict__ A1, const short* __restrict__ B1,   // yb [8192,1024], wprojT [1024,1024]
    const short* __restrict__ A2, const short* __restrict__ B2,   // hb [8192,HPAD], w3T [1024,HPAD]
    const float* __restrict__ X, float* __restrict__ Of)
{
    __shared__ short As[128 * 64];
    __shared__ short Bs[128 * 64];
    int t = threadIdx.x;
    int wid = t >> 6, l = t & 63;
    int wm = wid >> 1, wn = wid & 1;

    int nwg = gridDim.x, bid = blockIdx.x;
    int wg = (bid & 7) * (nwg >> 3) + (bid >> 3);
    int tiles_n = 8;                         // N = 1024
    int tm = wg / tiles_n, tn = wg % tiles_n;

    f32x4 acc[4][4];
    #pragma unroll
    for (int m = 0; m < 4; m++)
        #pragma unroll
        for (int n = 0; n < 4; n++) acc[m][n] = (f32x4){0.f, 0.f, 0.f, 0.f};

    #pragma unroll 1
    for (int phase = 0; phase < 2; phase++) {
        const short* Arow = phase == 0 ? A1 + (size_t)(tm * 128) * 1024 : A2 + (size_t)(tm * 128) * HPAD;
        const short* Brow = phase == 0 ? B1 + (size_t)(tn * 128) * 1024 : B2 + (size_t)(tn * 128) * HPAD;
        int K = phase == 0 ? 1024 : HPAD;
        for (int kt = 0; kt < K; kt += 64) {
            __syncthreads();
            #pragma unroll
            for (int i = 0; i < 4; i++) {
                int linear = i * 256 + t;
                int row = linear >> 3;
                int slot = linear & 7;
                int srcslot = slot ^ (row & 7);
                gload_lds16(Arow + (size_t)row * K + kt + srcslot * 8, (char*)As + linear * 16);
                gload_lds16(Brow + (size_t)row * K + kt + srcslot * 8, (char*)Bs + linear * 16);
            }
            __syncthreads();
            #pragma unroll
            for (int ks = 0; ks < 2; ks++) {
                bf16x8 af[4], bfr[4];
                #pragma unroll
                for (int m = 0; m < 4; m++) {
                    int row = wm * 64 + m * 16 + (l & 15);
                    af[m] = *(const bf16x8*)((char*)As + row * 128 + ((ks * 64 + (l >> 4) * 16) ^ ((row & 7) << 4)));
                }
                #pragma unroll
                for (int n = 0; n < 4; n++) {
                    int row = wn * 64 + n * 16 + (l & 15);
                    bfr[n] = *(const bf16x8*)((char*)Bs + row * 128 + ((ks * 64 + (l >> 4) * 16) ^ ((row & 7) << 4)));
                }
                #pragma unroll
                for (int m = 0; m < 4; m++)
                    #pragma unroll
                    for (int n = 0; n < 4; n++)
                        acc[m][n] = __builtin_amdgcn_mfma_f32_16x16x32_bf16(af[m], bfr[n], acc[m][n], 0, 0, 0);
            }
        }
    }

    #pragma unroll
    for (int m = 0; m < 4; m++)
        #pragma unroll
        for (int n = 0; n < 4; n++)
            #pragma unroll
            for (int r = 0; r < 4; r++) {
                int row = tm * 128 + wm * 64 + m * 16 + (l >> 4) * 4 + r;
                int col = tn * 128 + wn * 64 + n * 16 + (l & 15);
                size_t idx = (size_t)row * 1024 + col;
                Of[idx] = X[idx] + acc[m][n][r];
            }
}

// ---------------- attn body (blocks 0..511 of attn_mlp): bid-based XCD map identical
// to the standalone kernel. LDS: Ks bytes [0,16384), Vt bytes [16384,32768).
static __device__ void attn_body(const short* __restrict__ qkv, short* __restrict__ y,
                                 int bid, char* smem) {
    char* KsB = smem;
    char* VtB = smem + 16384;
    int xcd = bid & 7;
    int idx = bid >> 3;                 // 0..63
    int bh  = xcd + 8 * (idx >> 3);     // 8 heads per XCD
    int pair = idx & 7;                 // pass qt's: 15-pair, then pair
    int b = bh >> 4, h = bh & 15;
    int t = threadIdx.x, wid = t >> 6, l = t & 63;
    const size_t base = (size_t)b * TT * 3072;

    int krow = t >> 3, kslot = t & 7, ksrc = kslot ^ (krow & 7);
    int vrg = t >> 3, vch = t & 7;      // t<256: V rows 2vrg, 2vrg+1, d-chunk vch

    #pragma unroll
    for (int pass = 0; pass < 2; pass++) {
        int qt = pass == 0 ? (15 - pair) : pair;
        int q0 = qt * 128 + wid * 16;
        int qrow = q0 + (l & 15);        // this lane's q-row (S^T column)

        bf16x8 qf[2];
        #pragma unroll
        for (int s = 0; s < 2; s++) {
            int row = q0 + (l & 15);
            qf[s] = *(const bf16x8*)(qkv + base + (size_t)row * 3072 + h * 64 + s * 32 + (l >> 4) * 8);
        }

        f32x4 o[4];
        #pragma unroll
        for (int n = 0; n < 4; n++) o[n] = (f32x4){0.f, 0.f, 0.f, 0.f};
        float ll = 0.f;

        int nt = 2 * qt + 2;

        // prologue: stage tile 0 into buf 0
        {
            gload_lds16(qkv + base + (size_t)krow * 3072 + 1024 + h * 64 + ksrc * 8,
                        KsB + t * 16);
            if (t < 256) {
                uint4 va = *(const uint4*)(qkv + base + (size_t)(vrg * 2)     * 3072 + 2048 + h * 64 + vch * 8);
                uint4 vb = *(const uint4*)(qkv + base + (size_t)(vrg * 2 + 1) * 3072 + 2048 + h * 64 + vch * 8);
                const unsigned int* a32 = (const unsigned int*)&va;
                const unsigned int* b32 = (const unsigned int*)&vb;
                #pragma unroll
                for (int j = 0; j < 8; j++) {
                    int w = j >> 1;
                    unsigned int pack = __builtin_amdgcn_perm(b32[w], a32[w],
                                        (j & 1) ? 0x07060302u : 0x05040100u);
                    int d = vch * 8 + j;
                    int byte = (d * 128 + vrg * 4) ^ ((j ^ vch) << 4);
                    *(unsigned int*)(VtB + byte) = pack;
                }
            }
            __syncthreads();
        }

        int cur = 0;
        for (int it = 0; it < nt; ++it) {
            int kb = it << 6;
            bool have_next = (it + 1 < nt);
            uint4 va, vb;
            // 1. issue next-tile loads early (K async -> LDS[cur^1], V -> regs)
            if (have_next) {
                int nkb = kb + 64;
                gload_lds16(qkv + base + (size_t)(nkb + krow) * 3072 + 1024 + h * 64 + ksrc * 8,
                            KsB + (cur ^ 1) * 8192 + t * 16);
                if (t < 256) {
                    va = *(const uint4*)(qkv + base + (size_t)(nkb + vrg * 2)     * 3072 + 2048 + h * 64 + vch * 8);
                    vb = *(const uint4*)(qkv + base + (size_t)(nkb + vrg * 2 + 1) * 3072 + 2048 + h * 64 + vch * 8);
                }
            }
            // 2. compute current tile
            if (kb <= q0 + 15) {
                bool diag = (kb + 63 > q0);
                unsigned int pk[4][2];
                __builtin_amdgcn_s_setprio(1);
                #pragma unroll
                for (int j = 0; j < 4; j++) {
                    f32x4 z = (f32x4){0.f, 0.f, 0.f, 0.f};
                    #pragma unroll
                    for (int ks = 0; ks < 2; ks++) {
                        int row = j * 16 + (l & 15);
                        bf16x8 kf = *(const bf16x8*)(KsB + cur * 8192 + row * 128 +
                                    ((ks * 64 + (l >> 4) * 16) ^ ((row & 7) << 4)));
                        z = __builtin_amdgcn_mfma_f32_16x16x32_bf16(kf, qf[ks], z, 0, 0, 0);
                    }
                    float p[4];
                    #pragma unroll
                    for (int r = 0; r < 4; r++) {
                        float v = z[r];
                        if (diag) {
                            int kcol = kb + j * 16 + (l >> 4) * 4 + r;
                            if (kcol > qrow) v = -3e38f;
                        }
                        p[r] = exp2f(v);
                        ll += p[r];
                    }
                    pk[j][0] = __builtin_amdgcn_perm(fbits(p[1]), fbits(p[0]), 0x07060302u);
                    pk[j][1] = __builtin_amdgcn_perm(fbits(p[3]), fbits(p[2]), 0x07060302u);
                }
                __builtin_amdgcn_s_setprio(0);

                #pragma unroll
                for (int ks = 0; ks < 2; ks++) {
                    union { unsigned int u[4]; bf16x8 v; } pa;
                    #pragma unroll
                    for (int w = 0; w < 4; w++) {
                        int src = (((l >> 4) & 1) << 5) | ((w >> 1) << 4) | (l & 15);
                        unsigned int a = __shfl(pk[2 * ks][w & 1], src);
                        unsigned int bb = __shfl(pk[2 * ks + 1][w & 1], src);
                        pa.u[w] = (l >> 5) ? bb : a;
                    }
                    __builtin_amdgcn_s_setprio(1);
                    #pragma unroll
                    for (int n = 0; n < 4; n++) {
                        int vr = n * 16 + (l & 15);
                        int f = (vr & 7) ^ ((vr >> 3) & 7);
                        bf16x8 vf = *(const bf16x8*)(VtB + cur * 8192 + vr * 128 +
                                    ((ks * 64 + (l >> 4) * 16) ^ (f << 4)));
                        o[n] = __builtin_amdgcn_mfma_f32_16x16x32_bf16(pa.v, vf, o[n], 0, 0, 0);
                    }
                    __builtin_amdgcn_s_setprio(0);
                }
            }
            // 3. write next V to LDS (vmcnt wait on va/vb hidden under compute)
            if (have_next && t < 256) {
                const unsigned int* a32 = (const unsigned int*)&va;
                const unsigned int* b32 = (const unsigned int*)&vb;
                #pragma unroll
                for (int j = 0; j < 8; j++) {
                    int w = j >> 1;
                    unsigned int pack = __builtin_amdgcn_perm(b32[w], a32[w],
                                        (j & 1) ? 0x07060302u : 0x05040100u);
                    int d = vch * 8 + j;
                    int byte = (d * 128 + vrg * 4) ^ ((j ^ vch) << 4);
                    *(unsigned int*)(VtB + (cur ^ 1) * 8192 + byte) = pack;
                }
            }
            __syncthreads();
            cur ^= 1;
        }

        ll += __shfl_xor(ll, 16);
        ll += __shfl_xor(ll, 32);
        float inv = 1.f / ll;
        #pragma unroll
        for (int r = 0; r < 4; r++) {
            float invr = __shfl(inv, (l >> 4) * 4 + r);
            #pragma unroll
            for (int n = 0; n < 4; n++) {
                int row = q0 + (l >> 4) * 4 + r;
                int col = h * 64 + n * 16 + (l & 15);
                y[(size_t)(b * TT + row) * DM + col] = f2bf(o[n][r] * invr);
            }
        }
    }
}

// ---------------- mlp2 body (blocks 512.. of attn_mlp): hb = silu(A@W1) * (A@W2)
// LDS: As [0,16384), B1s [16384,32768), B2s [32768,49152).
static __device__ void mlp2_body(const short* __restrict__ A, const short* __restrict__ B1t,
                                 const short* __restrict__ B2t, short* __restrict__ Cb,
                                 int bid, int nwg, int N, int K, char* smem) {
    char* As  = smem;
    char* B1s = smem + 16384;
    char* B2s = smem + 32768;
    int t = threadIdx.x;
    int wid = t >> 6, l = t & 63;
    int wm = wid >> 2, wn = wid & 3;   // 2 x 4 waves

    int wg = (bid & 7) * (nwg >> 3) + (bid >> 3);
    int tiles_n = N >> 7;
    int tm = wg / tiles_n, tn = wg % tiles_n;

    const short* Arow  = A   + (size_t)(tm * 128) * K;
    const short* B1row = B1t + (size_t)(tn * 128) * K;
    const short* B2row = B2t + (size_t)(tn * 128) * K;

    f32x4 acc1[4][2], acc2[4][2];
    #pragma unroll
    for (int m = 0; m < 4; m++)
        #pragma unroll
        for (int n = 0; n < 2; n++) {
            acc1[m][n] = (f32x4){0.f, 0.f, 0.f, 0.f};
            acc2[m][n] = (f32x4){0.f, 0.f, 0.f, 0.f};
        }

    for (int kt = 0; kt < K; kt += 64) {
        __syncthreads();
        #pragma unroll
        for (int i = 0; i < 2; i++) {
            int linear = i * 512 + t;         // 0..1023
            int row = linear >> 3;
            int slot = linear & 7;
            int srcslot = slot ^ (row & 7);
            gload_lds16(Arow  + (size_t)row * K + kt + srcslot * 8, As  + linear * 16);
            gload_lds16(B1row + (size_t)row * K + kt + srcslot * 8, B1s + linear * 16);
            gload_lds16(B2row + (size_t)row * K + kt + srcslot * 8, B2s + linear * 16);
        }
        __syncthreads();
        #pragma unroll
        for (int ks = 0; ks < 2; ks++) {
            bf16x8 af[4], b1[2], b2[2];
            #pragma unroll
            for (int m = 0; m < 4; m++) {
                int row = wm * 64 + m * 16 + (l & 15);
                int off = (ks * 64 + (l >> 4) * 16) ^ ((row & 7) << 4);
                af[m] = *(const bf16x8*)(As + row * 128 + off);
            }
            #pragma unroll
            for (int n = 0; n < 2; n++) {
                int row = wn * 32 + n * 16 + (l & 15);
                int off = (ks * 64 + (l >> 4) * 16) ^ ((row & 7) << 4);
                b1[n] = *(const bf16x8*)(B1s + row * 128 + off);
                b2[n] = *(const bf16x8*)(B2s + row * 128 + off);
            }
            __builtin_amdgcn_s_setprio(1);
            #pragma unroll
            for (int m = 0; m < 4; m++)
                #pragma unroll
                for (int n = 0; n < 2; n++) {
                    acc1[m][n] = __builtin_amdgcn_mfma_f32_16x16x32_bf16(af[m], b1[n], acc1[m][n], 0, 0, 0);
                    acc2[m][n] = __builtin_amdgcn_mfma_f32_16x16x32_bf16(af[m], b2[n], acc2[m][n], 0, 0, 0);
                }
            __builtin_amdgcn_s_setprio(0);
        }
    }

    #pragma unroll
    for (int m = 0; m < 4; m++)
        #pragma unroll
        for (int n = 0; n < 2; n++)
            #pragma unroll
            for (int r = 0; r < 4; r++) {
                int row = tm * 128 + wm * 64 + m * 16 + (l >> 4) * 4 + r;
                int col = tn * 128 + wn * 32 + n * 16 + (l & 15);
                float v1 = acc1[m][n][r];
                float v2 = acc2[m][n][r];
                Cb[(size_t)row * N + col] = f2bf(v1 * (1.f / (1.f + __expf(-v1))) * v2);
            }
}

// ---------------- merged attn + mlp2: blocks 0..511 attn, 512..1919 mlp2.
// Independent work co-scheduled so attn's VALU-bound blocks overlap mlp2's
// MFMA-bound blocks on the same CUs (48KB LDS -> 3 blocks/CU mixed).
__global__ __launch_bounds__(512, 2) void attn_mlp(
    const short* __restrict__ qkv, short* __restrict__ y,
    const short* __restrict__ xn2, const short* __restrict__ w1t,
    const short* __restrict__ w2t, short* __restrict__ hb)
{
    __shared__ char smem[49152];
    int bid = blockIdx.x;
    if (bid < 512) attn_body(qkv, y, bid, smem);
    else           mlp2_body(xn2, w1t, w2t, hb, bid - 512, 1408, HPAD, 1024, smem);
}

extern "C" void kernel_launch(void* const* d_in, const int* in_sizes, int n_in,
                              void* d_out, int out_size, void* d_ws, size_t ws_size,
                              hipStream_t stream) {
    (void)in_sizes; (void)n_in; (void)out_size; (void)ws_size;
    const float* x      = (const float*)d_in[0];
    const float* w_attn = (const float*)d_in[1];
    const float* w_proj = (const float*)d_in[2];
    const float* w1     = (const float*)d_in[3];
    const float* w2     = (const float*)d_in[4];
    const float* w3     = (const float*)d_in[5];
    const float* g1     = (const float*)d_in[6];
    const float* g2     = (const float*)d_in[7];
    float* out = (float*)d_out;

    char* ws = (char*)d_ws;
    size_t off = 0;
    auto alloc = [&](size_t bytes) { char* p = ws + off; off += (bytes + 255) & ~(size_t)255; return p; };
    short* wattn_t = (short*)alloc((size_t)3072 * 1024 * 2);
    short* wproj_t = (short*)alloc((size_t)1024 * 1024 * 2);
    short* w1t     = (short*)alloc((size_t)HPAD * 1024 * 2);
    short* w2t     = (short*)alloc((size_t)HPAD * 1024 * 2);
    short* w3t     = (short*)alloc((size_t)1024 * HPAD * 2);
    short* xn1     = (short*)alloc((size_t)8192 * 1024 * 2);
    short* xn2     = (short*)alloc((size_t)8192 * 1024 * 2);
    short* qkvb    = (short*)alloc((size_t)8192 * 3072 * 2);
    short* yb      = (short*)alloc((size_t)8192 * 1024 * 2);
    short* hb      = (short*)alloc((size_t)8192 * HPAD * 2);

    dim3 tb(32, 8);
    wprep_all<<<12544, tb, 0, stream>>>(w_attn, w_proj, w1, w2, w3,
                                        wattn_t, wproj_t, w1t, w2t, w3t);

    rmsnorm2<<<8192, 256, 0, stream>>>(x, g1, g2, xn1, xn2);

    // qkv = xn1 @ w_attn^T (Q cols pre-scaled by SM_C); 768 blocks = 3/CU
    gemm256<5><<<768, 512, 0, stream>>>(xn1, wattn_t, qkvb, 3072, 1024);
    // attn (512 blocks) + mlp2 (1408 blocks) co-scheduled in one dispatch
    attn_mlp<<<1920, 512, 0, stream>>>(qkvb, yb, xn2, w1t, w2t, hb);
    // out = x + yb @ wproj^T + hb @ w3^T   (128x128, 512 blocks = 2/CU)
    gemm_fuse<<<512, 256, 0, stream>>>(yb, wproj_t, hb, w3t, x, out);
}

// Round 18
// 331.571 us; speedup vs baseline: 1.0126x; 1.0126x over previous
//
#include <hip/hip_runtime.h>

#define TT 2048
#define DM 1024
#define HPAD 2816
#define HID 2730
#define SM_C 0.18033688f   // 0.125 * log2(e)

typedef __attribute__((ext_vector_type(4))) float f32x4;
typedef __attribute__((ext_vector_type(8))) short bf16x8;

static __device__ __forceinline__ float bf2f(short u) {
    union { float f; unsigned int i; } c; c.i = ((unsigned int)(unsigned short)u) << 16; return c.f;
}
static __device__ __forceinline__ short f2bf(float f) {
    union { float f; unsigned int i; } c; c.f = f;
    unsigned int i = c.i;
    unsigned int r = (i + 0x7fffu + ((i >> 16) & 1u)) >> 16;
    return (short)r;
}
static __device__ __forceinline__ unsigned int fbits(float f) {
    union { float f; unsigned int i; } c; c.f = f;
    return c.i;
}

static __device__ __forceinline__ void gload_lds16(const void* g, void* l) {
    __builtin_amdgcn_global_load_lds(
        (const __attribute__((address_space(1))) unsigned int*)g,
        (__attribute__((address_space(3))) unsigned int*)l, 16, 0, 0);
}

// ---------------- merged weight transpose + cast (+pad), all 5 weights in one launch.
__global__ __launch_bounds__(256) void wprep_all(
    const float* __restrict__ w_attn, const float* __restrict__ w_proj,
    const float* __restrict__ w1, const float* __restrict__ w2, const float* __restrict__ w3,
    short* __restrict__ wattn_t, short* __restrict__ wproj_t,
    short* __restrict__ w1t, short* __restrict__ w2t, short* __restrict__ w3t)
{
    __shared__ float tile[32][33];
    int id = blockIdx.x;
    const float* in; short* out; int K, N, Kpad, Npad, nbx;
    if (id < 3072)      {            in = w_attn; out = wattn_t; K = 1024; N = 3072; Kpad = 1024; Npad = 3072; nbx = 32; }
    else if (id < 4096) { id -= 3072; in = w_proj; out = wproj_t; K = 1024; N = 1024; Kpad = 1024; Npad = 1024; nbx = 32; }
    else if (id < 6912) { id -= 4096; in = w1;     out = w1t;     K = 1024; N = HID;  Kpad = 1024; Npad = HPAD; nbx = 32; }
    else if (id < 9728) { id -= 6912; in = w2;     out = w2t;     K = 1024; N = HID;  Kpad = 1024; Npad = HPAD; nbx = 32; }
    else                { id -= 9728; in = w3;     out = w3t;     K = HID;  N = 1024; Kpad = HPAD; Npad = 1024; nbx = 88; }
    int kb = (id % nbx) * 32, nb = (id / nbx) * 32;
    int tx = threadIdx.x, ty = threadIdx.y; // 32 x 8
    #pragma unroll
    for (int i = 0; i < 32; i += 8) {
        int k = kb + ty + i, n = nb + tx;
        float v = (k < K && n < N) ? in[(size_t)k * N + n] : 0.f;
        tile[tx][ty + i] = v;
    }
    __syncthreads();
    #pragma unroll
    for (int i = 0; i < 32; i += 8) {
        int n = nb + ty + i, k = kb + tx;
        if (n < Npad && k < Kpad) out[(size_t)n * Kpad + k] = f2bf(tile[ty + i][tx]);
    }
}

// ---------------- fused double RMSNorm: x f32 [8192,1024] -> xn1, xn2 bf16
__global__ __launch_bounds__(256) void rmsnorm2(const float* __restrict__ x,
    const float* __restrict__ g1, const float* __restrict__ g2,
    short* __restrict__ xn1, short* __restrict__ xn2) {
    int row = blockIdx.x;
    const float* xr = x + (size_t)row * DM;
    int t = threadIdx.x;
    float4 v = ((const float4*)xr)[t];
    float ss = v.x*v.x + v.y*v.y + v.z*v.z + v.w*v.w;
    #pragma unroll
    for (int off = 1; off < 64; off <<= 1) ss += __shfl_xor(ss, off);
    __shared__ float red[4];
    if ((t & 63) == 0) red[t >> 6] = ss;
    __syncthreads();
    float tot = red[0] + red[1] + red[2] + red[3];
    float rs = rsqrtf(tot * (1.0f / DM) + 1e-6f);
    float4 G1 = ((const float4*)g1)[t];
    float4 G2 = ((const float4*)g2)[t];
    union { short s[4]; int2 v; } o1, o2;
    o1.s[0] = f2bf(v.x * rs * G1.x); o1.s[1] = f2bf(v.y * rs * G1.y);
    o1.s[2] = f2bf(v.z * rs * G1.z); o1.s[3] = f2bf(v.w * rs * G1.w);
    o2.s[0] = f2bf(v.x * rs * G2.x); o2.s[1] = f2bf(v.y * rs * G2.y);
    o2.s[2] = f2bf(v.z * rs * G2.z); o2.s[3] = f2bf(v.w * rs * G2.w);
    *(int2*)(xn1 + (size_t)row * DM + t * 4) = o1.v;
    *(int2*)(xn2 + (size_t)row * DM + t * 4) = o2.v;
}

// ---------------- bf16 GEMM, BM=256 x BN=128, BK=64, 512 thr / 8 waves (4m x 2n).
// EPI 5: Cb = acc bf16, cols < 1024 pre-scaled by SM_C (qkv: Q prescale)
template<int EPI>
__global__ __launch_bounds__(512, 4) void gemm256(
    const short* __restrict__ A, const short* __restrict__ Bt,
    short* __restrict__ Cb, int N, int K)
{
    __shared__ short As[256 * 64];   // 32KB
    __shared__ short Bs[128 * 64];   // 16KB
    int t = threadIdx.x;
    int wid = t >> 6, l = t & 63;
    int wm = wid >> 1, wn = wid & 1;

    int nwg = gridDim.x, bid = blockIdx.x;
    int wg = (bid & 7) * (nwg >> 3) + (bid >> 3);   // XCD swizzle (grids %8==0)
    int tiles_n = N >> 7;
    int tm = wg / tiles_n, tn = wg % tiles_n;

    f32x4 acc[4][4];
    #pragma unroll
    for (int m = 0; m < 4; m++)
        #pragma unroll
        for (int n = 0; n < 4; n++) acc[m][n] = (f32x4){0.f, 0.f, 0.f, 0.f};

    const short* Apan = A + (size_t)(tm * 256) * K;
    const short* Bpan = Bt + (size_t)(tn * 128) * K;

    for (int kt = 0; kt < K; kt += 64) {
        __syncthreads();
        #pragma unroll
        for (int i = 0; i < 4; i++) {
            int lin = i * 512 + t;            // 0..2047 -> A rows 0..255
            int row = lin >> 3;
            int slot = lin & 7;
            int src = slot ^ (row & 7);       // pre-swizzled source, linear LDS dest
            gload_lds16(Apan + (size_t)row * K + kt + src * 8, (char*)As + lin * 16);
        }
        #pragma unroll
        for (int i = 0; i < 2; i++) {
            int lin = i * 512 + t;            // 0..1023 -> B rows 0..127
            int row = lin >> 3;
            int slot = lin & 7;
            int src = slot ^ (row & 7);
            gload_lds16(Bpan + (size_t)row * K + kt + src * 8, (char*)Bs + lin * 16);
        }
        __syncthreads();
        #pragma unroll
        for (int ks = 0; ks < 2; ks++) {
            bf16x8 af[4], bfr[4];
            #pragma unroll
            for (int m = 0; m < 4; m++) {
                int row = wm * 64 + m * 16 + (l & 15);
                af[m] = *(const bf16x8*)((char*)As + row * 128 + ((ks * 64 + (l >> 4) * 16) ^ ((row & 7) << 4)));
            }
            #pragma unroll
            for (int n = 0; n < 4; n++) {
                int row = wn * 64 + n * 16 + (l & 15);
                bfr[n] = *(const bf16x8*)((char*)Bs + row * 128 + ((ks * 64 + (l >> 4) * 16) ^ ((row & 7) << 4)));
            }
            __builtin_amdgcn_s_setprio(1);
            #pragma unroll
            for (int m = 0; m < 4; m++)
                #pragma unroll
                for (int n = 0; n < 4; n++)
                    acc[m][n] = __builtin_amdgcn_mfma_f32_16x16x32_bf16(af[m], bfr[n], acc[m][n], 0, 0, 0);
            __builtin_amdgcn_s_setprio(0);
        }
    }

    bool qcols = (EPI == 5) && (tn < 8);   // block-uniform: qkv cols < 1024
    #pragma unroll
    for (int m = 0; m < 4; m++)
        #pragma unroll
        for (int n = 0; n < 4; n++)
            #pragma unroll
            for (int r = 0; r < 4; r++) {
                int row = tm * 256 + wm * 64 + m * 16 + (l >> 4) * 4 + r;
                int col = tn * 128 + wn * 64 + n * 16 + (l & 15);
                size_t idx = (size_t)row * N + col;
                float v = acc[m][n][r];
                if constexpr (EPI == 5) Cb[idx] = f2bf(qcols ? v * SM_C : v);
                else Cb[idx] = f2bf(v);
            }
}

// ---------------- fused attn-proj + MLP-down + residual (128x128, 256 thr, grid 512):
// out = x + yb@wprojT + hb@w3T
__global__ __launch_bounds__(256) void gemm_fuse(
    const short* __restrict__ A1, const short* __restrict__ B1,   // yb [8192,1024], wprojT [1024,1024]
    const short* __restrict__ A2, const short* __restrict__ B2,   // hb [8192,HPAD], w3T [1024,HPAD]
    const float* __restrict__ X, float* __restrict__ Of)
{
    __shared__ short As[128 * 64];
    __shared__ short Bs[128 * 64];
    int t = threadIdx.x;
    int wid = t >> 6, l = t & 63;
    int wm = wid >> 1, wn = wid & 1;

    int nwg = gridDim.x, bid = blockIdx.x;
    int wg = (bid & 7) * (nwg >> 3) + (bid >> 3);
    int tiles_n = 8;                         // N = 1024
    int tm = wg / tiles_n, tn = wg % tiles_n;

    f32x4 acc[4][4];
    #pragma unroll
    for (int m = 0; m < 4; m++)
        #pragma unroll
        for (int n = 0; n < 4; n++) acc[m][n] = (f32x4){0.f, 0.f, 0.f, 0.f};

    #pragma unroll 1
    for (int phase = 0; phase < 2; phase++) {
        const short* Arow = phase == 0 ? A1 + (size_t)(tm * 128) * 1024 : A2 + (size_t)(tm * 128) * HPAD;
        const short* Brow = phase == 0 ? B1 + (size_t)(tn * 128) * 1024 : B2 + (size_t)(tn * 128) * HPAD;
        int K = phase == 0 ? 1024 : HPAD;
        for (int kt = 0; kt < K; kt += 64) {
            __syncthreads();
            #pragma unroll
            for (int i = 0; i < 4; i++) {
                int linear = i * 256 + t;
                int row = linear >> 3;
                int slot = linear & 7;
                int srcslot = slot ^ (row & 7);
                gload_lds16(Arow + (size_t)row * K + kt + srcslot * 8, (char*)As + linear * 16);
                gload_lds16(Brow + (size_t)row * K + kt + srcslot * 8, (char*)Bs + linear * 16);
            }
            __syncthreads();
            #pragma unroll
            for (int ks = 0; ks < 2; ks++) {
                bf16x8 af[4], bfr[4];
                #pragma unroll
                for (int m = 0; m < 4; m++) {
                    int row = wm * 64 + m * 16 + (l & 15);
                    af[m] = *(const bf16x8*)((char*)As + row * 128 + ((ks * 64 + (l >> 4) * 16) ^ ((row & 7) << 4)));
                }
                #pragma unroll
                for (int n = 0; n < 4; n++) {
                    int row = wn * 64 + n * 16 + (l & 15);
                    bfr[n] = *(const bf16x8*)((char*)Bs + row * 128 + ((ks * 64 + (l >> 4) * 16) ^ ((row & 7) << 4)));
                }
                #pragma unroll
                for (int m = 0; m < 4; m++)
                    #pragma unroll
                    for (int n = 0; n < 4; n++)
                        acc[m][n] = __builtin_amdgcn_mfma_f32_16x16x32_bf16(af[m], bfr[n], acc[m][n], 0, 0, 0);
            }
        }
    }

    #pragma unroll
    for (int m = 0; m < 4; m++)
        #pragma unroll
        for (int n = 0; n < 4; n++)
            #pragma unroll
            for (int r = 0; r < 4; r++) {
                int row = tm * 128 + wm * 64 + m * 16 + (l >> 4) * 4 + r;
                int col = tn * 128 + wn * 64 + n * 16 + (l & 15);
                size_t idx = (size_t)row * 1024 + col;
                Of[idx] = X[idx] + acc[m][n][r];
            }
}

// ---------------- fused MLP dual-B GEMM: hb = silu(A@W1) * (A@W2)
// 512 threads / 8 waves (2m x 4n), BM=BN=128, BK=64, LDS 48KB.
__global__ __launch_bounds__(512, 2) void gemm_mlp2(
    const short* __restrict__ A, const short* __restrict__ B1t, const short* __restrict__ B2t,
    short* __restrict__ Cb, int M, int N, int K)
{
    __shared__ short As[128 * 64];
    __shared__ short B1s[128 * 64];
    __shared__ short B2s[128 * 64];
    int t = threadIdx.x;
    int wid = t >> 6, l = t & 63;
    int wm = wid >> 2, wn = wid & 3;   // 2 x 4 waves

    int nwg = gridDim.x, bid = blockIdx.x;
    int wg = (bid & 7) * (nwg >> 3) + (bid >> 3);
    int tiles_n = N >> 7;
    int tm = wg / tiles_n, tn = wg % tiles_n;

    const short* Arow  = A   + (size_t)(tm * 128) * K;
    const short* B1row = B1t + (size_t)(tn * 128) * K;
    const short* B2row = B2t + (size_t)(tn * 128) * K;

    f32x4 acc1[4][2], acc2[4][2];
    #pragma unroll
    for (int m = 0; m < 4; m++)
        #pragma unroll
        for (int n = 0; n < 2; n++) {
            acc1[m][n] = (f32x4){0.f, 0.f, 0.f, 0.f};
            acc2[m][n] = (f32x4){0.f, 0.f, 0.f, 0.f};
        }

    for (int kt = 0; kt < K; kt += 64) {
        __syncthreads();
        #pragma unroll
        for (int i = 0; i < 2; i++) {
            int linear = i * 512 + t;         // 0..1023
            int row = linear >> 3;
            int slot = linear & 7;
            int srcslot = slot ^ (row & 7);
            gload_lds16(Arow  + (size_t)row * K + kt + srcslot * 8, (char*)As  + linear * 16);
            gload_lds16(B1row + (size_t)row * K + kt + srcslot * 8, (char*)B1s + linear * 16);
            gload_lds16(B2row + (size_t)row * K + kt + srcslot * 8, (char*)B2s + linear * 16);
        }
        __syncthreads();
        #pragma unroll
        for (int ks = 0; ks < 2; ks++) {
            bf16x8 af[4], b1[2], b2[2];
            #pragma unroll
            for (int m = 0; m < 4; m++) {
                int row = wm * 64 + m * 16 + (l & 15);
                int off = (ks * 64 + (l >> 4) * 16) ^ ((row & 7) << 4);
                af[m] = *(const bf16x8*)((char*)As + row * 128 + off);
            }
            #pragma unroll
            for (int n = 0; n < 2; n++) {
                int row = wn * 32 + n * 16 + (l & 15);
                int off = (ks * 64 + (l >> 4) * 16) ^ ((row & 7) << 4);
                b1[n] = *(const bf16x8*)((char*)B1s + row * 128 + off);
                b2[n] = *(const bf16x8*)((char*)B2s + row * 128 + off);
            }
            #pragma unroll
            for (int m = 0; m < 4; m++)
                #pragma unroll
                for (int n = 0; n < 2; n++) {
                    acc1[m][n] = __builtin_amdgcn_mfma_f32_16x16x32_bf16(af[m], b1[n], acc1[m][n], 0, 0, 0);
                    acc2[m][n] = __builtin_amdgcn_mfma_f32_16x16x32_bf16(af[m], b2[n], acc2[m][n], 0, 0, 0);
                }
        }
    }

    #pragma unroll
    for (int m = 0; m < 4; m++)
        #pragma unroll
        for (int n = 0; n < 2; n++)
            #pragma unroll
            for (int r = 0; r < 4; r++) {
                int row = tm * 128 + wm * 64 + m * 16 + (l >> 4) * 4 + r;
                int col = tn * 128 + wn * 32 + n * 16 + (l & 15);
                float v1 = acc1[m][n][r];
                float v2 = acc2[m][n][r];
                Cb[(size_t)row * N + col] = f2bf(v1 * (1.f / (1.f + __expf(-v1))) * v2);
            }
}

// ---------------- causal flash attention: qkv bf16 [B*T,3072] -> y bf16 [B*T,1024]
// KVBLK=64, double-buffered, swapped QK^T, in-register P (Q pre-scaled in qkv GEMM).
__global__ __launch_bounds__(512, 4) void attn(const short* __restrict__ qkv, short* __restrict__ y) {
    __shared__ short Ks[2][64 * 64];   // [buf][kv][d], swizzled
    __shared__ short Vt[2][64 * 64];   // [buf][d][kv], swizzled
    int bid = blockIdx.x;
    int xcd = bid & 7;
    int idx = bid >> 3;                 // 0..63
    int bh  = xcd + 8 * (idx >> 3);     // 8 heads per XCD
    int pair = idx & 7;                 // pass qt's: 15-pair, then pair
    int b = bh >> 4, h = bh & 15;
    int t = threadIdx.x, wid = t >> 6, l = t & 63;
    const size_t base = (size_t)b * TT * 3072;

    int krow = t >> 3, kslot = t & 7, ksrc = kslot ^ (krow & 7);
    int vrg = t >> 3, vch = t & 7;      // t<256: V rows 2vrg, 2vrg+1, d-chunk vch

    #pragma unroll
    for (int pass = 0; pass < 2; pass++) {
        int qt = pass == 0 ? (15 - pair) : pair;
        int q0 = qt * 128 + wid * 16;
        int qrow = q0 + (l & 15);        // this lane's q-row (S^T column)

        bf16x8 qf[2];
        #pragma unroll
        for (int s = 0; s < 2; s++) {
            int row = q0 + (l & 15);
            qf[s] = *(const bf16x8*)(qkv + base + (size_t)row * 3072 + h * 64 + s * 32 + (l >> 4) * 8);
        }

        f32x4 o[4];
        #pragma unroll
        for (int n = 0; n < 4; n++) o[n] = (f32x4){0.f, 0.f, 0.f, 0.f};
        float ll = 0.f;

        int nt = 2 * qt + 2;

        // prologue: stage tile 0 into buf 0
        {
            gload_lds16(qkv + base + (size_t)krow * 3072 + 1024 + h * 64 + ksrc * 8,
                        (char*)Ks + t * 16);
            if (t < 256) {
                uint4 va = *(const uint4*)(qkv + base + (size_t)(vrg * 2)     * 3072 + 2048 + h * 64 + vch * 8);
                uint4 vb = *(const uint4*)(qkv + base + (size_t)(vrg * 2 + 1) * 3072 + 2048 + h * 64 + vch * 8);
                const unsigned int* a32 = (const unsigned int*)&va;
                const unsigned int* b32 = (const unsigned int*)&vb;
                #pragma unroll
                for (int j = 0; j < 8; j++) {
                    int w = j >> 1;
                    unsigned int pack = __builtin_amdgcn_perm(b32[w], a32[w],
                                        (j & 1) ? 0x07060302u : 0x05040100u);
                    int d = vch * 8 + j;
                    int byte = (d * 128 + vrg * 4) ^ ((j ^ vch) << 4);
                    *(unsigned int*)((char*)Vt + byte) = pack;
                }
            }
            __syncthreads();
        }

        int cur = 0;
        for (int it = 0; it < nt; ++it) {
            int kb = it << 6;
            bool have_next = (it + 1 < nt);
            uint4 va, vb;
            // 1. issue next-tile loads early (K async -> LDS[cur^1], V -> regs)
            if (have_next) {
                int nkb = kb + 64;
                gload_lds16(qkv + base + (size_t)(nkb + krow) * 3072 + 1024 + h * 64 + ksrc * 8,
                            (char*)Ks + (cur ^ 1) * 8192 + t * 16);
                if (t < 256) {
                    va = *(const uint4*)(qkv + base + (size_t)(nkb + vrg * 2)     * 3072 + 2048 + h * 64 + vch * 8);
                    vb = *(const uint4*)(qkv + base + (size_t)(nkb + vrg * 2 + 1) * 3072 + 2048 + h * 64 + vch * 8);
                }
            }
            // 2. compute current tile
            if (kb <= q0 + 15) {
                bool diag = (kb + 63 > q0);
                unsigned int pk[4][2];
                __builtin_amdgcn_s_setprio(1);
                #pragma unroll
                for (int j = 0; j < 4; j++) {
                    f32x4 z = (f32x4){0.f, 0.f, 0.f, 0.f};
                    #pragma unroll
                    for (int ks = 0; ks < 2; ks++) {
                        int row = j * 16 + (l & 15);
                        bf16x8 kf = *(const bf16x8*)((char*)Ks + cur * 8192 + row * 128 +
                                    ((ks * 64 + (l >> 4) * 16) ^ ((row & 7) << 4)));
                        z = __builtin_amdgcn_mfma_f32_16x16x32_bf16(kf, qf[ks], z, 0, 0, 0);
                    }
                    float p[4];
                    #pragma unroll
                    for (int r = 0; r < 4; r++) {
                        float v = z[r];
                        if (diag) {
                            int kcol = kb + j * 16 + (l >> 4) * 4 + r;
                            if (kcol > qrow) v = -3e38f;
                        }
                        p[r] = exp2f(v);
                        ll += p[r];
                    }
                    pk[j][0] = __builtin_amdgcn_perm(fbits(p[1]), fbits(p[0]), 0x07060302u);
                    pk[j][1] = __builtin_amdgcn_perm(fbits(p[3]), fbits(p[2]), 0x07060302u);
                }
                __builtin_amdgcn_s_setprio(0);

                #pragma unroll
                for (int ks = 0; ks < 2; ks++) {
                    union { unsigned int u[4]; bf16x8 v; } pa;
                    #pragma unroll
                    for (int w = 0; w < 4; w++) {
                        int src = (((l >> 4) & 1) << 5) | ((w >> 1) << 4) | (l & 15);
                        unsigned int a = __shfl(pk[2 * ks][w & 1], src);
                        unsigned int bb = __shfl(pk[2 * ks + 1][w & 1], src);
                        pa.u[w] = (l >> 5) ? bb : a;
                    }
                    __builtin_amdgcn_s_setprio(1);
                    #pragma unroll
                    for (int n = 0; n < 4; n++) {
                        int vr = n * 16 + (l & 15);
                        int f = (vr & 7) ^ ((vr >> 3) & 7);
                        bf16x8 vf = *(const bf16x8*)((char*)Vt + cur * 8192 + vr * 128 +
                                    ((ks * 64 + (l >> 4) * 16) ^ (f << 4)));
                        o[n] = __builtin_amdgcn_mfma_f32_16x16x32_bf16(pa.v, vf, o[n], 0, 0, 0);
                    }
                    __builtin_amdgcn_s_setprio(0);
                }
            }
            // 3. write next V to LDS (vmcnt wait on va/vb hidden under compute)
            if (have_next && t < 256) {
                const unsigned int* a32 = (const unsigned int*)&va;
                const unsigned int* b32 = (const unsigned int*)&vb;
                #pragma unroll
                for (int j = 0; j < 8; j++) {
                    int w = j >> 1;
                    unsigned int pack = __builtin_amdgcn_perm(b32[w], a32[w],
                                        (j & 1) ? 0x07060302u : 0x05040100u);
                    int d = vch * 8 + j;
                    int byte = (d * 128 + vrg * 4) ^ ((j ^ vch) << 4);
                    *(unsigned int*)((char*)Vt + (cur ^ 1) * 8192 + byte) = pack;
                }
            }
            __syncthreads();
            cur ^= 1;
        }

        ll += __shfl_xor(ll, 16);
        ll += __shfl_xor(ll, 32);
        float inv = 1.f / ll;
        #pragma unroll
        for (int r = 0; r < 4; r++) {
            float invr = __shfl(inv, (l >> 4) * 4 + r);
            #pragma unroll
            for (int n = 0; n < 4; n++) {
                int row = q0 + (l >> 4) * 4 + r;
                int col = h * 64 + n * 16 + (l & 15);
                y[(size_t)(b * TT + row) * DM + col] = f2bf(o[n][r] * invr);
            }
        }
    }
}

extern "C" void kernel_launch(void* const* d_in, const int* in_sizes, int n_in,
                              void* d_out, int out_size, void* d_ws, size_t ws_size,
                              hipStream_t stream) {
    (void)in_sizes; (void)n_in; (void)out_size; (void)ws_size;
    const float* x      = (const float*)d_in[0];
    const float* w_attn = (const float*)d_in[1];
    const float* w_proj = (const float*)d_in[2];
    const float* w1     = (const float*)d_in[3];
    const float* w2     = (const float*)d_in[4];
    const float* w3     = (const float*)d_in[5];
    const float* g1     = (const float*)d_in[6];
    const float* g2     = (const float*)d_in[7];
    float* out = (float*)d_out;

    char* ws = (char*)d_ws;
    size_t off = 0;
    auto alloc = [&](size_t bytes) { char* p = ws + off; off += (bytes + 255) & ~(size_t)255; return p; };
    short* wattn_t = (short*)alloc((size_t)3072 * 1024 * 2);
    short* wproj_t = (short*)alloc((size_t)1024 * 1024 * 2);
    short* w1t     = (short*)alloc((size_t)HPAD * 1024 * 2);
    short* w2t     = (short*)alloc((size_t)HPAD * 1024 * 2);
    short* w3t     = (short*)alloc((size_t)1024 * HPAD * 2);
    short* xn1     = (short*)alloc((size_t)8192 * 1024 * 2);
    short* xn2     = (short*)alloc((size_t)8192 * 1024 * 2);
    short* qkvb    = (short*)alloc((size_t)8192 * 3072 * 2);
    short* yb      = (short*)alloc((size_t)8192 * 1024 * 2);
    short* hb      = (short*)alloc((size_t)8192 * HPAD * 2);

    dim3 tb(32, 8);
    wprep_all<<<12544, tb, 0, stream>>>(w_attn, w_proj, w1, w2, w3,
                                        wattn_t, wproj_t, w1t, w2t, w3t);

    rmsnorm2<<<8192, 256, 0, stream>>>(x, g1, g2, xn1, xn2);

    // qkv = xn1 @ w_attn^T (Q cols pre-scaled by SM_C); 768 blocks = 3/CU
    gemm256<5><<<768, 512, 0, stream>>>(xn1, wattn_t, qkvb, 3072, 1024);
    attn<<<512, 512, 0, stream>>>(qkvb, yb);
    gemm_mlp2<<<1408, 512, 0, stream>>>(xn2, w1t, w2t, hb, 8192, HPAD, 1024);
    // out = x + yb @ wproj^T + hb @ w3^T   (128x128, 512 blocks = 2/CU)
    gemm_fuse<<<512, 256, 0, stream>>>(yb, wproj_t, hb, w3t, x, out);
}